// Round 9
// baseline (268.083 us; speedup 1.0000x reference)
//
#include <hip/hip_runtime.h>
#include <hip/hip_bf16.h>

#define TT 200
#define EE 64
#define NT 7          // 7 tiles x 32 rows = 224 (rows 200..223 zero-weighted)

typedef unsigned short u16;
typedef unsigned int u32;
typedef __attribute__((ext_vector_type(8))) short bfrag;   // 8 bf16 in 4 VGPRs
typedef __attribute__((ext_vector_type(4))) float f32x4;

__device__ __forceinline__ u16 f2bf(float f) {
    __hip_bfloat16 h(f);                       // RNE HW cvt
    return __builtin_bit_cast(u16, h);
}
__device__ __forceinline__ float bf2f(u16 h) {
    return __uint_as_float(((u32)h) << 16);
}
__device__ __forceinline__ float sigmoid_fast(float x) {
    return __builtin_amdgcn_rcpf(1.0f + __expf(-x));
}

// Pack W1q^T, W1k^T and W2^T into MFMA *A*-fragment order for swapped GEMMs.
// GEMM1/GEMMq: A slot (g=l>>4, ks, j) <-> k = ks*32 + g*8 + j, m = mt5*16 + l15
// GEMM2: custom bijection matching h1's C-layout residency:
//   i24 = ks*8+j; i24<20: (mt5=i24>>2, r=i24&3), k = mt5*16 + g*4 + r
__global__ void prep_frags(const float* __restrict__ W1, const float* __restrict__ W2,
                           u16* __restrict__ A1p, u16* __restrict__ A2p,
                           u16* __restrict__ A1q) {
    int idx = blockIdx.x * 256 + threadIdx.x;
    if (idx < 5 * 2 * 64 * 8) {   // 5 m-tiles (80) x 2 k-chunks (64)
        int j = idx & 7, l = (idx >> 3) & 63, ks = (idx >> 9) & 1, mt5 = idx >> 10;
        int g = l >> 4, m = mt5 * 16 + (l & 15);
        int k = ks * 32 + g * 8 + j;
        A1p[idx] = f2bf(W1[(64 + k) * 80 + m]);   // key half
        A1q[idx] = f2bf(W1[k * 80 + m]);          // query half
    }
    if (idx < 3 * 3 * 64 * 8) {   // 3 m-tiles (40->48) x 3 k-chunks (80->96)
        int j = idx & 7, l = (idx >> 3) & 63, ks = (idx >> 9) % 3, m2 = idx / 1536;
        int g = l >> 4, m = m2 * 16 + (l & 15);
        int i24 = ks * 8 + j;
        u16 v = 0;
        if (i24 < 20 && m < 40) {
            int mt5 = i24 >> 2, r = i24 & 3;
            int k = mt5 * 16 + g * 4 + r;
            v = f2bf(W2[k * 40 + m]);
        }
        A2p[idx] = v;
    }
}

// load 32 rows (2 groups of 16): group A rows MT*32+l15, group B rows +16
#define LOADK32(MT, QA0, QA1, QA2, QA3, QB0, QB1, QB2, QB3) {           \
    int ra_ = (MT) * 32 + l15;                                          \
    QA0 = QA1 = QA2 = QA3 = make_float4(0.f, 0.f, 0.f, 0.f);            \
    QB0 = QB1 = QB2 = QB3 = make_float4(0.f, 0.f, 0.f, 0.f);            \
    if (ra_ < TT) {                                                     \
        const float* p_ = kb + ra_ * EE + g * 8;                        \
        QA0 = *reinterpret_cast<const float4*>(p_);                     \
        QA1 = *reinterpret_cast<const float4*>(p_ + 4);                 \
        QA2 = *reinterpret_cast<const float4*>(p_ + 32);                \
        QA3 = *reinterpret_cast<const float4*>(p_ + 36);                \
    }                                                                   \
    if (ra_ + 16 < TT) {                                                \
        const float* p_ = kb + (ra_ + 16) * EE + g * 8;                 \
        QB0 = *reinterpret_cast<const float4*>(p_);                     \
        QB1 = *reinterpret_cast<const float4*>(p_ + 4);                 \
        QB2 = *reinterpret_cast<const float4*>(p_ + 32);                \
        QB3 = *reinterpret_cast<const float4*>(p_ + 36);                \
    } }

#define PACK(A, X, Y) {                                                 \
    A[0] = (short)f2bf(X.x); A[1] = (short)f2bf(X.y);                   \
    A[2] = (short)f2bf(X.z); A[3] = (short)f2bf(X.w);                   \
    A[4] = (short)f2bf(Y.x); A[5] = (short)f2bf(Y.y);                   \
    A[6] = (short)f2bf(Y.z); A[7] = (short)f2bf(Y.w); }

// One batch per WAVE; weights block-shared in LDS; 32 rows/iter; fixed-base
// softmax (scores provably bounded by sum|wk|+|bias| ~ 7.2 -> exp(s) safe).
__global__ __launch_bounds__(256, 3) void din_mfma(
    const float* __restrict__ queries,     // (B,1,64)
    const float* __restrict__ keys,        // (B,200,64)
    const int*   __restrict__ keys_length, // (B,1)
    const float* __restrict__ b1,          // (80)
    const float* __restrict__ b2,          // (40)
    const float* __restrict__ wk,          // (40)
    const float* __restrict__ bias,        // (1)
    const u16*   __restrict__ A1p,
    const u16*   __restrict__ A2p,
    const u16*   __restrict__ A1q,
    float* __restrict__ out)               // (B,1,64)
{
    __shared__ __align__(16) u16 w1ls[5 * 2 * 64 * 8];   // 10240 B
    __shared__ __align__(16) u16 w2ls[3 * 3 * 64 * 8];   //  9216 B
    __shared__ __align__(16) float wkls[48];
    __shared__ __align__(16) float b2ls[48];
    __shared__ __align__(16) float qils[4][80];          // per-wave qb1, C-layout order

    const int tid  = threadIdx.x;
    const int lane = tid & 63;
    const int wv   = tid >> 6;
    const int l15  = lane & 15;
    const int g    = lane >> 4;
    const int b    = blockIdx.x * 4 + wv;

    const float* kb = keys + (size_t)b * (TT * EE);
    const float* q  = queries + (size_t)b * EE;
    const int len   = keys_length[b];
    const float biass = bias[0];

    // --- stage weight frags + wk/b2 into LDS (coalesced) ---
    for (int c = tid; c < 640; c += 256)
        *reinterpret_cast<float4*>(&w1ls[c * 8]) = reinterpret_cast<const float4*>(A1p)[c];
    for (int c = tid; c < 576; c += 256)
        *reinterpret_cast<float4*>(&w2ls[c * 8]) = reinterpret_cast<const float4*>(A2p)[c];
    if (tid < 48) {
        wkls[tid] = (tid < 40) ? wk[tid] : 0.f;
        b2ls[tid] = (tid < 40) ? b2[tid] : 0.f;
    }

    // --- qb1 via MFMA: B = q replicated across all 16 cols -> D[m][n]=qb1pre[m] ---
    {
        bfrag qf0, qf1;
        const float* qp = q + g * 8;
        float4 q0 = *reinterpret_cast<const float4*>(qp);
        float4 q1 = *reinterpret_cast<const float4*>(qp + 4);
        float4 q2 = *reinterpret_cast<const float4*>(qp + 32);
        float4 q3 = *reinterpret_cast<const float4*>(qp + 36);
        PACK(qf0, q0, q1); PACK(qf1, q2, q3);
        #pragma unroll
        for (int mt5 = 0; mt5 < 5; ++mt5) {
            bfrag aq0 = *reinterpret_cast<const bfrag*>(A1q + (((mt5 * 2 + 0) * 64 + lane) << 3));
            bfrag aq1 = *reinterpret_cast<const bfrag*>(A1q + (((mt5 * 2 + 1) * 64 + lane) << 3));
            f32x4 c = { 0.f, 0.f, 0.f, 0.f };
            c = __builtin_amdgcn_mfma_f32_16x16x32_bf16(aq0, qf0, c, 0, 0, 0);
            c = __builtin_amdgcn_mfma_f32_16x16x32_bf16(aq1, qf1, c, 0, 0, 0);
            float4 bv = *reinterpret_cast<const float4*>(b1 + mt5 * 16 + g * 4);
            if (l15 == 0) {
                float4 o = { c[0] + bv.x, c[1] + bv.y, c[2] + bv.z, c[3] + bv.w };
                *reinterpret_cast<float4*>(&qils[wv][mt5 * 16 + g * 4]) = o;
            }
        }
    }
    __syncthreads();   // the ONLY block barrier: LDS tables ready

    // --- fixed-base softmax state (per-lane partials, reduced in epilogue) ---
    float acc[16];
    #pragma unroll
    for (int j = 0; j < 16; ++j) acc[j] = 0.f;
    float Z = 0.f;

    // 1-deep prefetch of 32-row tiles
    float4 qa0, qa1, qa2, qa3, qb0, qb1_, qb2, qb3;
    LOADK32(0, qa0, qa1, qa2, qa3, qb0, qb1_, qb2, qb3);
    bfrag a0, a1, a2, a3;   // a0/a1 = group A feats; a2/a3 = group B
    PACK(a0, qa0, qa1); PACK(a1, qa2, qa3);
    PACK(a2, qb0, qb1_); PACK(a3, qb2, qb3);

    for (int mt = 0; mt < NT; ++mt) {
        if (mt + 1 < NT) { LOADK32(mt + 1, qa0, qa1, qa2, qa3, qb0, qb1_, qb2, qb3); }

        // GEMM1 group A -> sigmoid -> frags (d dead before group B: low liveness)
        bfrag xa0, xa1, xa2, xb0, xb1, xb2;
        {
            f32x4 d[5];
            #pragma unroll
            for (int mt5 = 0; mt5 < 5; ++mt5) {
                bfrag wA = *reinterpret_cast<const bfrag*>(&w1ls[((mt5 * 2 + 0) * 64 + lane) * 8]);
                bfrag wB = *reinterpret_cast<const bfrag*>(&w1ls[((mt5 * 2 + 1) * 64 + lane) * 8]);
                f32x4 c = *reinterpret_cast<const f32x4*>(&qils[wv][mt5 * 16 + g * 4]);
                c = __builtin_amdgcn_mfma_f32_16x16x32_bf16(wA, a0, c, 0, 0, 0);
                c = __builtin_amdgcn_mfma_f32_16x16x32_bf16(wB, a1, c, 0, 0, 0);
                d[mt5] = c;
            }
            #pragma unroll
            for (int j = 0; j < 8; ++j) {
                xa0[j] = (short)f2bf(sigmoid_fast(d[j >> 2][j & 3]));
                xa1[j] = (short)f2bf(sigmoid_fast(d[(8 + j) >> 2][(8 + j) & 3]));
                xa2[j] = (short)((16 + j) < 20
                            ? f2bf(sigmoid_fast(d[(16 + j) >> 2][(16 + j) & 3])) : 0);
            }
        }
        // GEMM1 group B -> sigmoid -> frags
        {
            f32x4 d[5];
            #pragma unroll
            for (int mt5 = 0; mt5 < 5; ++mt5) {
                bfrag wA = *reinterpret_cast<const bfrag*>(&w1ls[((mt5 * 2 + 0) * 64 + lane) * 8]);
                bfrag wB = *reinterpret_cast<const bfrag*>(&w1ls[((mt5 * 2 + 1) * 64 + lane) * 8]);
                f32x4 c = *reinterpret_cast<const f32x4*>(&qils[wv][mt5 * 16 + g * 4]);
                c = __builtin_amdgcn_mfma_f32_16x16x32_bf16(wA, a2, c, 0, 0, 0);
                c = __builtin_amdgcn_mfma_f32_16x16x32_bf16(wB, a3, c, 0, 0, 0);
                d[mt5] = c;
            }
            #pragma unroll
            for (int j = 0; j < 8; ++j) {
                xb0[j] = (short)f2bf(sigmoid_fast(d[j >> 2][j & 3]));
                xb1[j] = (short)f2bf(sigmoid_fast(d[(8 + j) >> 2][(8 + j) & 3]));
                xb2[j] = (short)((16 + j) < 20
                            ? f2bf(sigmoid_fast(d[(16 + j) >> 2][(16 + j) & 3])) : 0);
            }
        }

        // GEMM2 swapped + wk-dot folded; each u-frag read serves both groups
        float pa = 0.f, pb = 0.f;
        #pragma unroll
        for (int m2 = 0; m2 < 3; ++m2) {
            bfrag u0 = *reinterpret_cast<const bfrag*>(&w2ls[((m2 * 3 + 0) * 64 + lane) * 8]);
            bfrag u1 = *reinterpret_cast<const bfrag*>(&w2ls[((m2 * 3 + 1) * 64 + lane) * 8]);
            bfrag u2 = *reinterpret_cast<const bfrag*>(&w2ls[((m2 * 3 + 2) * 64 + lane) * 8]);
            f32x4 ci = *reinterpret_cast<const f32x4*>(&b2ls[m2 * 16 + g * 4]);
            f32x4 wv4 = *reinterpret_cast<const f32x4*>(&wkls[m2 * 16 + g * 4]);
            f32x4 ca = ci, cb = ci;
            ca = __builtin_amdgcn_mfma_f32_16x16x32_bf16(u0, xa0, ca, 0, 0, 0);
            ca = __builtin_amdgcn_mfma_f32_16x16x32_bf16(u1, xa1, ca, 0, 0, 0);
            ca = __builtin_amdgcn_mfma_f32_16x16x32_bf16(u2, xa2, ca, 0, 0, 0);
            cb = __builtin_amdgcn_mfma_f32_16x16x32_bf16(u0, xb0, cb, 0, 0, 0);
            cb = __builtin_amdgcn_mfma_f32_16x16x32_bf16(u1, xb1, cb, 0, 0, 0);
            cb = __builtin_amdgcn_mfma_f32_16x16x32_bf16(u2, xb2, cb, 0, 0, 0);
            #pragma unroll
            for (int rr = 0; rr < 4; ++rr) {
                pa = fmaf(sigmoid_fast(ca[rr]), wv4[rr], pa);
                pb = fmaf(sigmoid_fast(cb[rr]), wv4[rr], pb);
            }
        }
        pa += __shfl_xor(pa, 16); pa += __shfl_xor(pa, 32);
        pb += __shfl_xor(pb, 16); pb += __shfl_xor(pb, 32);

        // fixed-base exp weights; |score| <= sum|wk|+|bias| (~7.2) -> no overflow.
        // len==0 -> ref softmaxes all-equal mask values -> uniform weights.
        const int ra = mt * 32 + l15, rb = ra + 16;
        float ea = (ra < len) ? __expf(pa + biass) : ((len == 0 && ra < TT) ? 1.f : 0.f);
        float eb = (rb < len) ? __expf(pb + biass) : ((len == 0 && rb < TT) ? 1.f : 0.f);
        Z += ea + eb;

        // fused pooling: both rows' keys still in the bf16 fragments
        #pragma unroll
        for (int j = 0; j < 8; ++j) {
            acc[j]     = fmaf(ea, bf2f((u16)a0[j]), fmaf(eb, bf2f((u16)a2[j]), acc[j]));
            acc[8 + j] = fmaf(ea, bf2f((u16)a1[j]), fmaf(eb, bf2f((u16)a3[j]), acc[8 + j]));
        }

        if (mt + 1 < NT) {
            PACK(a0, qa0, qa1); PACK(a1, qa2, qa3);
            PACK(a2, qb0, qb1_); PACK(a3, qb2, qb3);
        }
    }

    // reduce Z + pooled features over the 16 t-row lanes; lanes l15==0 write out
    Z += __shfl_xor(Z, 1); Z += __shfl_xor(Z, 2);
    Z += __shfl_xor(Z, 4); Z += __shfl_xor(Z, 8);
    #pragma unroll
    for (int j = 0; j < 16; ++j) {
        acc[j] += __shfl_xor(acc[j], 1);
        acc[j] += __shfl_xor(acc[j], 2);
        acc[j] += __shfl_xor(acc[j], 4);
        acc[j] += __shfl_xor(acc[j], 8);
    }
    if (l15 == 0) {
        float inv = __builtin_amdgcn_rcpf(Z);
        float* ob = out + (size_t)b * EE + g * 8;
        float4 o0 = { acc[0] * inv,  acc[1] * inv,  acc[2] * inv,  acc[3] * inv };
        float4 o1 = { acc[4] * inv,  acc[5] * inv,  acc[6] * inv,  acc[7] * inv };
        float4 o2 = { acc[8] * inv,  acc[9] * inv,  acc[10] * inv, acc[11] * inv };
        float4 o3 = { acc[12] * inv, acc[13] * inv, acc[14] * inv, acc[15] * inv };
        *reinterpret_cast<float4*>(ob)      = o0;
        *reinterpret_cast<float4*>(ob + 4)  = o1;
        *reinterpret_cast<float4*>(ob + 32) = o2;
        *reinterpret_cast<float4*>(ob + 36) = o3;
    }
}

extern "C" void kernel_launch(void* const* d_in, const int* in_sizes, int n_in,
                              void* d_out, int out_size, void* d_ws, size_t ws_size,
                              hipStream_t stream) {
    const float* queries = (const float*)d_in[0];
    const float* keys    = (const float*)d_in[1];
    const int*   klen    = (const int*)d_in[2];
    const float* W1      = (const float*)d_in[3];
    const float* b1      = (const float*)d_in[4];
    const float* W2      = (const float*)d_in[5];
    const float* b2      = (const float*)d_in[6];
    const float* wk      = (const float*)d_in[7];
    const float* bias    = (const float*)d_in[8];
    float* out           = (float*)d_out;

    u16* A1p = (u16*)d_ws;                                 // 10240 B
    u16* A2p = (u16*)((char*)d_ws + 10240);                //  9216 B
    u16* A1q = (u16*)((char*)d_ws + 19456);                // 10240 B

    prep_frags<<<20, 256, 0, stream>>>(W1, W2, A1p, A2p, A1q);
    din_mfma<<<1024, 256, 0, stream>>>(queries, keys, klen, b1, b2, wk, bias,
                                       A1p, A2p, A1q, out);
}

// Round 10
// 62.227 us; speedup vs baseline: 4.3082x; 4.3082x over previous
//
#include <hip/hip_runtime.h>
#include <hip/hip_bf16.h>

#define TT 200
#define EE 64
#define NT 7          // 7 tiles x 32 rows = 224 (rows 200..223 zero-weighted)

typedef unsigned short u16;
typedef unsigned int u32;
typedef __attribute__((ext_vector_type(8))) short bfrag;   // 8 bf16 in 4 VGPRs
typedef __attribute__((ext_vector_type(4))) float f32x4;

__device__ __forceinline__ u16 f2bf(float f) {
    __hip_bfloat16 h(f);                       // RNE HW cvt
    return __builtin_bit_cast(u16, h);
}
__device__ __forceinline__ float bf2f(u16 h) {
    return __uint_as_float(((u32)h) << 16);
}
__device__ __forceinline__ float sigmoid_fast(float x) {
    return __builtin_amdgcn_rcpf(1.0f + __expf(-x));
}

// Pack W1q^T, W1k^T and W2^T into MFMA *A*-fragment order for swapped GEMMs.
// GEMM1/GEMMq: A slot (g=l>>4, ks, j) <-> k = ks*32 + g*8 + j, m = mt5*16 + l15
// GEMM2: custom bijection matching h1's C-layout residency:
//   i24 = ks*8+j; i24<20: (mt5=i24>>2, r=i24&3), k = mt5*16 + g*4 + r
__global__ void prep_frags(const float* __restrict__ W1, const float* __restrict__ W2,
                           u16* __restrict__ A1p, u16* __restrict__ A2p,
                           u16* __restrict__ A1q) {
    int idx = blockIdx.x * 256 + threadIdx.x;
    if (idx < 5 * 2 * 64 * 8) {   // 5 m-tiles (80) x 2 k-chunks (64)
        int j = idx & 7, l = (idx >> 3) & 63, ks = (idx >> 9) & 1, mt5 = idx >> 10;
        int g = l >> 4, m = mt5 * 16 + (l & 15);
        int k = ks * 32 + g * 8 + j;
        A1p[idx] = f2bf(W1[(64 + k) * 80 + m]);   // key half
        A1q[idx] = f2bf(W1[k * 80 + m]);          // query half
    }
    if (idx < 3 * 3 * 64 * 8) {   // 3 m-tiles (40->48) x 3 k-chunks (80->96)
        int j = idx & 7, l = (idx >> 3) & 63, ks = (idx >> 9) % 3, m2 = idx / 1536;
        int g = l >> 4, m = m2 * 16 + (l & 15);
        int i24 = ks * 8 + j;
        u16 v = 0;
        if (i24 < 20 && m < 40) {
            int mt5 = i24 >> 2, r = i24 & 3;
            int k = mt5 * 16 + g * 4 + r;
            v = f2bf(W2[k * 40 + m]);
        }
        A2p[idx] = v;
    }
}

// load 32 rows (2 groups of 16): group A rows MT*32+l15, group B rows +16
#define LOADK32(MT, QA0, QA1, QA2, QA3, QB0, QB1, QB2, QB3) {           \
    int ra_ = (MT) * 32 + l15;                                          \
    QA0 = QA1 = QA2 = QA3 = make_float4(0.f, 0.f, 0.f, 0.f);            \
    QB0 = QB1 = QB2 = QB3 = make_float4(0.f, 0.f, 0.f, 0.f);            \
    if (ra_ < TT) {                                                     \
        const float* p_ = kb + ra_ * EE + g * 8;                        \
        QA0 = *reinterpret_cast<const float4*>(p_);                     \
        QA1 = *reinterpret_cast<const float4*>(p_ + 4);                 \
        QA2 = *reinterpret_cast<const float4*>(p_ + 32);                \
        QA3 = *reinterpret_cast<const float4*>(p_ + 36);                \
    }                                                                   \
    if (ra_ + 16 < TT) {                                                \
        const float* p_ = kb + (ra_ + 16) * EE + g * 8;                 \
        QB0 = *reinterpret_cast<const float4*>(p_);                     \
        QB1 = *reinterpret_cast<const float4*>(p_ + 4);                 \
        QB2 = *reinterpret_cast<const float4*>(p_ + 32);                \
        QB3 = *reinterpret_cast<const float4*>(p_ + 36);                \
    } }

#define PACK(A, X, Y) {                                                 \
    A[0] = (short)f2bf(X.x); A[1] = (short)f2bf(X.y);                   \
    A[2] = (short)f2bf(X.z); A[3] = (short)f2bf(X.w);                   \
    A[4] = (short)f2bf(Y.x); A[5] = (short)f2bf(Y.y);                   \
    A[6] = (short)f2bf(Y.z); A[7] = (short)f2bf(Y.w); }

// One batch per WAVE; weights block-shared in LDS; 32 rows/iter; fixed-base
// softmax (scores provably bounded by sum|wk|+|bias| ~ 7.2 -> exp(s) safe).
// launch_bounds(256,2): empirically VGPR cap = 256/N; N=2 -> 128 (no spill).
__global__ __launch_bounds__(256, 2) void din_mfma(
    const float* __restrict__ queries,     // (B,1,64)
    const float* __restrict__ keys,        // (B,200,64)
    const int*   __restrict__ keys_length, // (B,1)
    const float* __restrict__ b1,          // (80)
    const float* __restrict__ b2,          // (40)
    const float* __restrict__ wk,          // (40)
    const float* __restrict__ bias,        // (1)
    const u16*   __restrict__ A1p,
    const u16*   __restrict__ A2p,
    const u16*   __restrict__ A1q,
    float* __restrict__ out)               // (B,1,64)
{
    __shared__ __align__(16) u16 w1ls[5 * 2 * 64 * 8];   // 10240 B
    __shared__ __align__(16) u16 w2ls[3 * 3 * 64 * 8];   //  9216 B
    __shared__ __align__(16) float wkls[48];
    __shared__ __align__(16) float b2ls[48];
    __shared__ __align__(16) float qils[4][80];          // per-wave qb1, C-layout order

    const int tid  = threadIdx.x;
    const int lane = tid & 63;
    const int wv   = tid >> 6;
    const int l15  = lane & 15;
    const int g    = lane >> 4;
    const int b    = blockIdx.x * 4 + wv;

    const float* kb = keys + (size_t)b * (TT * EE);
    const float* q  = queries + (size_t)b * EE;
    const int len   = keys_length[b];
    const float biass = bias[0];

    // --- stage weight frags + wk/b2 into LDS (coalesced) ---
    for (int c = tid; c < 640; c += 256)
        *reinterpret_cast<float4*>(&w1ls[c * 8]) = reinterpret_cast<const float4*>(A1p)[c];
    for (int c = tid; c < 576; c += 256)
        *reinterpret_cast<float4*>(&w2ls[c * 8]) = reinterpret_cast<const float4*>(A2p)[c];
    if (tid < 48) {
        wkls[tid] = (tid < 40) ? wk[tid] : 0.f;
        b2ls[tid] = (tid < 40) ? b2[tid] : 0.f;
    }

    // --- qb1 via MFMA: B = q replicated across all 16 cols -> D[m][n]=qb1pre[m] ---
    {
        bfrag qf0, qf1;
        const float* qp = q + g * 8;
        float4 q0 = *reinterpret_cast<const float4*>(qp);
        float4 q1 = *reinterpret_cast<const float4*>(qp + 4);
        float4 q2 = *reinterpret_cast<const float4*>(qp + 32);
        float4 q3 = *reinterpret_cast<const float4*>(qp + 36);
        PACK(qf0, q0, q1); PACK(qf1, q2, q3);
        #pragma unroll
        for (int mt5 = 0; mt5 < 5; ++mt5) {
            bfrag aq0 = *reinterpret_cast<const bfrag*>(A1q + (((mt5 * 2 + 0) * 64 + lane) << 3));
            bfrag aq1 = *reinterpret_cast<const bfrag*>(A1q + (((mt5 * 2 + 1) * 64 + lane) << 3));
            f32x4 c = { 0.f, 0.f, 0.f, 0.f };
            c = __builtin_amdgcn_mfma_f32_16x16x32_bf16(aq0, qf0, c, 0, 0, 0);
            c = __builtin_amdgcn_mfma_f32_16x16x32_bf16(aq1, qf1, c, 0, 0, 0);
            float4 bv = *reinterpret_cast<const float4*>(b1 + mt5 * 16 + g * 4);
            if (l15 == 0) {
                float4 o = { c[0] + bv.x, c[1] + bv.y, c[2] + bv.z, c[3] + bv.w };
                *reinterpret_cast<float4*>(&qils[wv][mt5 * 16 + g * 4]) = o;
            }
        }
    }
    __syncthreads();   // the ONLY block barrier: LDS tables ready

    // --- fixed-base softmax state (per-lane partials, reduced in epilogue) ---
    float acc[16];
    #pragma unroll
    for (int j = 0; j < 16; ++j) acc[j] = 0.f;
    float Z = 0.f;

    // 1-deep prefetch of 32-row tiles
    float4 qa0, qa1, qa2, qa3, qb0, qb1_, qb2, qb3;
    LOADK32(0, qa0, qa1, qa2, qa3, qb0, qb1_, qb2, qb3);
    bfrag a0, a1, a2, a3;   // a0/a1 = group A feats; a2/a3 = group B
    PACK(a0, qa0, qa1); PACK(a1, qa2, qa3);
    PACK(a2, qb0, qb1_); PACK(a3, qb2, qb3);

    for (int mt = 0; mt < NT; ++mt) {
        if (mt + 1 < NT) { LOADK32(mt + 1, qa0, qa1, qa2, qa3, qb0, qb1_, qb2, qb3); }

        // GEMM1 group A -> sigmoid -> frags (d dead before group B: low liveness)
        bfrag xa0, xa1, xa2, xb0, xb1, xb2;
        {
            f32x4 d[5];
            #pragma unroll
            for (int mt5 = 0; mt5 < 5; ++mt5) {
                bfrag wA = *reinterpret_cast<const bfrag*>(&w1ls[((mt5 * 2 + 0) * 64 + lane) * 8]);
                bfrag wB = *reinterpret_cast<const bfrag*>(&w1ls[((mt5 * 2 + 1) * 64 + lane) * 8]);
                f32x4 c = *reinterpret_cast<const f32x4*>(&qils[wv][mt5 * 16 + g * 4]);
                c = __builtin_amdgcn_mfma_f32_16x16x32_bf16(wA, a0, c, 0, 0, 0);
                c = __builtin_amdgcn_mfma_f32_16x16x32_bf16(wB, a1, c, 0, 0, 0);
                d[mt5] = c;
            }
            #pragma unroll
            for (int j = 0; j < 8; ++j) {
                xa0[j] = (short)f2bf(sigmoid_fast(d[j >> 2][j & 3]));
                xa1[j] = (short)f2bf(sigmoid_fast(d[(8 + j) >> 2][(8 + j) & 3]));
                xa2[j] = (short)((16 + j) < 20
                            ? f2bf(sigmoid_fast(d[(16 + j) >> 2][(16 + j) & 3])) : 0);
            }
        }
        // GEMM1 group B -> sigmoid -> frags
        {
            f32x4 d[5];
            #pragma unroll
            for (int mt5 = 0; mt5 < 5; ++mt5) {
                bfrag wA = *reinterpret_cast<const bfrag*>(&w1ls[((mt5 * 2 + 0) * 64 + lane) * 8]);
                bfrag wB = *reinterpret_cast<const bfrag*>(&w1ls[((mt5 * 2 + 1) * 64 + lane) * 8]);
                f32x4 c = *reinterpret_cast<const f32x4*>(&qils[wv][mt5 * 16 + g * 4]);
                c = __builtin_amdgcn_mfma_f32_16x16x32_bf16(wA, a2, c, 0, 0, 0);
                c = __builtin_amdgcn_mfma_f32_16x16x32_bf16(wB, a3, c, 0, 0, 0);
                d[mt5] = c;
            }
            #pragma unroll
            for (int j = 0; j < 8; ++j) {
                xb0[j] = (short)f2bf(sigmoid_fast(d[j >> 2][j & 3]));
                xb1[j] = (short)f2bf(sigmoid_fast(d[(8 + j) >> 2][(8 + j) & 3]));
                xb2[j] = (short)((16 + j) < 20
                            ? f2bf(sigmoid_fast(d[(16 + j) >> 2][(16 + j) & 3])) : 0);
            }
        }

        // GEMM2 swapped + wk-dot folded; each u-frag read serves both groups
        float pa = 0.f, pb = 0.f;
        #pragma unroll
        for (int m2 = 0; m2 < 3; ++m2) {
            bfrag u0 = *reinterpret_cast<const bfrag*>(&w2ls[((m2 * 3 + 0) * 64 + lane) * 8]);
            bfrag u1 = *reinterpret_cast<const bfrag*>(&w2ls[((m2 * 3 + 1) * 64 + lane) * 8]);
            bfrag u2 = *reinterpret_cast<const bfrag*>(&w2ls[((m2 * 3 + 2) * 64 + lane) * 8]);
            f32x4 ci = *reinterpret_cast<const f32x4*>(&b2ls[m2 * 16 + g * 4]);
            f32x4 wv4 = *reinterpret_cast<const f32x4*>(&wkls[m2 * 16 + g * 4]);
            f32x4 ca = ci, cb = ci;
            ca = __builtin_amdgcn_mfma_f32_16x16x32_bf16(u0, xa0, ca, 0, 0, 0);
            ca = __builtin_amdgcn_mfma_f32_16x16x32_bf16(u1, xa1, ca, 0, 0, 0);
            ca = __builtin_amdgcn_mfma_f32_16x16x32_bf16(u2, xa2, ca, 0, 0, 0);
            cb = __builtin_amdgcn_mfma_f32_16x16x32_bf16(u0, xb0, cb, 0, 0, 0);
            cb = __builtin_amdgcn_mfma_f32_16x16x32_bf16(u1, xb1, cb, 0, 0, 0);
            cb = __builtin_amdgcn_mfma_f32_16x16x32_bf16(u2, xb2, cb, 0, 0, 0);
            #pragma unroll
            for (int rr = 0; rr < 4; ++rr) {
                pa = fmaf(sigmoid_fast(ca[rr]), wv4[rr], pa);
                pb = fmaf(sigmoid_fast(cb[rr]), wv4[rr], pb);
            }
        }
        pa += __shfl_xor(pa, 16); pa += __shfl_xor(pa, 32);
        pb += __shfl_xor(pb, 16); pb += __shfl_xor(pb, 32);

        // fixed-base exp weights; |score| <= sum|wk|+|bias| (~7.2) -> no overflow.
        // len==0 -> ref softmaxes all-equal mask values -> uniform weights.
        const int ra = mt * 32 + l15, rb = ra + 16;
        float ea = (ra < len) ? __expf(pa + biass) : ((len == 0 && ra < TT) ? 1.f : 0.f);
        float eb = (rb < len) ? __expf(pb + biass) : ((len == 0 && rb < TT) ? 1.f : 0.f);
        Z += ea + eb;

        // fused pooling: both rows' keys still in the bf16 fragments
        #pragma unroll
        for (int j = 0; j < 8; ++j) {
            acc[j]     = fmaf(ea, bf2f((u16)a0[j]), fmaf(eb, bf2f((u16)a2[j]), acc[j]));
            acc[8 + j] = fmaf(ea, bf2f((u16)a1[j]), fmaf(eb, bf2f((u16)a3[j]), acc[8 + j]));
        }

        if (mt + 1 < NT) {
            PACK(a0, qa0, qa1); PACK(a1, qa2, qa3);
            PACK(a2, qb0, qb1_); PACK(a3, qb2, qb3);
        }
    }

    // reduce Z + pooled features over the 16 t-row lanes; lanes l15==0 write out
    Z += __shfl_xor(Z, 1); Z += __shfl_xor(Z, 2);
    Z += __shfl_xor(Z, 4); Z += __shfl_xor(Z, 8);
    #pragma unroll
    for (int j = 0; j < 16; ++j) {
        acc[j] += __shfl_xor(acc[j], 1);
        acc[j] += __shfl_xor(acc[j], 2);
        acc[j] += __shfl_xor(acc[j], 4);
        acc[j] += __shfl_xor(acc[j], 8);
    }
    if (l15 == 0) {
        float inv = __builtin_amdgcn_rcpf(Z);
        float* ob = out + (size_t)b * EE + g * 8;
        float4 o0 = { acc[0] * inv,  acc[1] * inv,  acc[2] * inv,  acc[3] * inv };
        float4 o1 = { acc[4] * inv,  acc[5] * inv,  acc[6] * inv,  acc[7] * inv };
        float4 o2 = { acc[8] * inv,  acc[9] * inv,  acc[10] * inv, acc[11] * inv };
        float4 o3 = { acc[12] * inv, acc[13] * inv, acc[14] * inv, acc[15] * inv };
        *reinterpret_cast<float4*>(ob)      = o0;
        *reinterpret_cast<float4*>(ob + 4)  = o1;
        *reinterpret_cast<float4*>(ob + 32) = o2;
        *reinterpret_cast<float4*>(ob + 36) = o3;
    }
}

extern "C" void kernel_launch(void* const* d_in, const int* in_sizes, int n_in,
                              void* d_out, int out_size, void* d_ws, size_t ws_size,
                              hipStream_t stream) {
    const float* queries = (const float*)d_in[0];
    const float* keys    = (const float*)d_in[1];
    const int*   klen    = (const int*)d_in[2];
    const float* W1      = (const float*)d_in[3];
    const float* b1      = (const float*)d_in[4];
    const float* W2      = (const float*)d_in[5];
    const float* b2      = (const float*)d_in[6];
    const float* wk      = (const float*)d_in[7];
    const float* bias    = (const float*)d_in[8];
    float* out           = (float*)d_out;

    u16* A1p = (u16*)d_ws;                                 // 10240 B
    u16* A2p = (u16*)((char*)d_ws + 10240);                //  9216 B
    u16* A1q = (u16*)((char*)d_ws + 19456);                // 10240 B

    prep_frags<<<20, 256, 0, stream>>>(W1, W2, A1p, A2p, A1q);
    din_mfma<<<1024, 256, 0, stream>>>(queries, keys, klen, b1, b2, wk, bias,
                                       A1p, A2p, A1q, out);
}

// Round 11
// 50.912 us; speedup vs baseline: 5.2656x; 1.2222x over previous
//
#include <hip/hip_runtime.h>
#include <hip/hip_bf16.h>

#define TT 200
#define EE 64
#define NT 7          // max tiles: 7 x 32 rows = 224

typedef unsigned short u16;
typedef unsigned int u32;
typedef __attribute__((ext_vector_type(8))) short bfrag;   // 8 bf16 in 4 VGPRs
typedef __attribute__((ext_vector_type(4))) float f32x4;

__device__ __forceinline__ u16 f2bf(float f) {
    __hip_bfloat16 h(f);                       // RNE HW cvt
    return __builtin_bit_cast(u16, h);
}
__device__ __forceinline__ float bf2f(u16 h) {
    return __uint_as_float(((u32)h) << 16);
}
__device__ __forceinline__ float sigmoid_fast(float x) {
    return __builtin_amdgcn_rcpf(1.0f + __expf(-x));
}

// Pack W1q^T, W1k^T and W2^T into MFMA *A*-fragment order for swapped GEMMs.
// GEMM1/GEMMq: A slot (g=l>>4, ks, j) <-> k = ks*32 + g*8 + j, m = mt5*16 + l15
// GEMM2: custom bijection matching h1's C-layout residency:
//   i24 = ks*8+j; i24<20: (mt5=i24>>2, r=i24&3), k = mt5*16 + g*4 + r
__global__ void prep_frags(const float* __restrict__ W1, const float* __restrict__ W2,
                           u16* __restrict__ A1p, u16* __restrict__ A2p,
                           u16* __restrict__ A1q) {
    int idx = blockIdx.x * 256 + threadIdx.x;
    if (idx < 5 * 2 * 64 * 8) {   // 5 m-tiles (80) x 2 k-chunks (64)
        int j = idx & 7, l = (idx >> 3) & 63, ks = (idx >> 9) & 1, mt5 = idx >> 10;
        int g = l >> 4, m = mt5 * 16 + (l & 15);
        int k = ks * 32 + g * 8 + j;
        A1p[idx] = f2bf(W1[(64 + k) * 80 + m]);   // key half
        A1q[idx] = f2bf(W1[k * 80 + m]);          // query half
    }
    if (idx < 3 * 3 * 64 * 8) {   // 3 m-tiles (40->48) x 3 k-chunks (80->96)
        int j = idx & 7, l = (idx >> 3) & 63, ks = (idx >> 9) % 3, m2 = idx / 1536;
        int g = l >> 4, m = m2 * 16 + (l & 15);
        int i24 = ks * 8 + j;
        u16 v = 0;
        if (i24 < 20 && m < 40) {
            int mt5 = i24 >> 2, r = i24 & 3;
            int k = mt5 * 16 + g * 4 + r;
            v = f2bf(W2[k * 40 + m]);
        }
        A2p[idx] = v;
    }
}

// load 32 rows (2 groups of 16): group A rows MT*32+l15, group B rows +16.
// Rows >= lenEff are never needed (weight exactly 0) -> skip their loads.
#define LOADK32(MT, QA0, QA1, QA2, QA3, QB0, QB1, QB2, QB3) {           \
    int ra_ = (MT) * 32 + l15;                                          \
    QA0 = QA1 = QA2 = QA3 = make_float4(0.f, 0.f, 0.f, 0.f);            \
    QB0 = QB1 = QB2 = QB3 = make_float4(0.f, 0.f, 0.f, 0.f);            \
    if (ra_ < lenEff) {                                                 \
        const float* p_ = kb + ra_ * EE + g * 8;                        \
        QA0 = *reinterpret_cast<const float4*>(p_);                     \
        QA1 = *reinterpret_cast<const float4*>(p_ + 4);                 \
        QA2 = *reinterpret_cast<const float4*>(p_ + 32);                \
        QA3 = *reinterpret_cast<const float4*>(p_ + 36);                \
    }                                                                   \
    if (ra_ + 16 < lenEff) {                                            \
        const float* p_ = kb + (ra_ + 16) * EE + g * 8;                 \
        QB0 = *reinterpret_cast<const float4*>(p_);                     \
        QB1 = *reinterpret_cast<const float4*>(p_ + 4);                 \
        QB2 = *reinterpret_cast<const float4*>(p_ + 32);                \
        QB3 = *reinterpret_cast<const float4*>(p_ + 36);                \
    } }

#define PACK(A, X, Y) {                                                 \
    A[0] = (short)f2bf(X.x); A[1] = (short)f2bf(X.y);                   \
    A[2] = (short)f2bf(X.z); A[3] = (short)f2bf(X.w);                   \
    A[4] = (short)f2bf(Y.x); A[5] = (short)f2bf(Y.y);                   \
    A[6] = (short)f2bf(Y.z); A[7] = (short)f2bf(Y.w); }

// One batch per WAVE; weights block-shared in LDS; 32 rows/iter; fixed-base
// softmax (scores provably bounded by sum|wk|+|bias| ~ 7.2 -> exp(s) safe).
// Early-exit: tiles entirely beyond keys_length are skipped (weight == 0).
__global__ __launch_bounds__(256, 2) void din_mfma(
    const float* __restrict__ queries,     // (B,1,64)
    const float* __restrict__ keys,        // (B,200,64)
    const int*   __restrict__ keys_length, // (B,1)
    const float* __restrict__ b1,          // (80)
    const float* __restrict__ b2,          // (40)
    const float* __restrict__ wk,          // (40)
    const float* __restrict__ bias,        // (1)
    const u16*   __restrict__ A1p,
    const u16*   __restrict__ A2p,
    const u16*   __restrict__ A1q,
    float* __restrict__ out)               // (B,1,64)
{
    __shared__ __align__(16) u16 w1ls[5 * 2 * 64 * 8];   // 10240 B
    __shared__ __align__(16) u16 w2ls[3 * 3 * 64 * 8];   //  9216 B
    __shared__ __align__(16) float wkls[48];
    __shared__ __align__(16) float b2ls[48];
    __shared__ __align__(16) float qils[4][80];          // per-wave qb1, C-layout order

    const int tid  = threadIdx.x;
    const int lane = tid & 63;
    const int wv   = tid >> 6;
    const int l15  = lane & 15;
    const int g    = lane >> 4;
    const int b    = blockIdx.x * 4 + wv;

    const float* kb = keys + (size_t)b * (TT * EE);
    const float* q  = queries + (size_t)b * EE;
    const int len   = keys_length[b];
    const float biass = bias[0];

    // len==0: ref softmaxes all-equal masked scores -> uniform over all TT rows.
    const int lenEff = (len == 0) ? TT : len;
    const int ntiles = (lenEff + 31) >> 5;   // 1..7

    // --- stage weight frags + wk/b2 into LDS (coalesced) ---
    for (int c = tid; c < 640; c += 256)
        *reinterpret_cast<float4*>(&w1ls[c * 8]) = reinterpret_cast<const float4*>(A1p)[c];
    for (int c = tid; c < 576; c += 256)
        *reinterpret_cast<float4*>(&w2ls[c * 8]) = reinterpret_cast<const float4*>(A2p)[c];
    if (tid < 48) {
        wkls[tid] = (tid < 40) ? wk[tid] : 0.f;
        b2ls[tid] = (tid < 40) ? b2[tid] : 0.f;
    }

    // --- qb1 via MFMA: B = q replicated across all 16 cols -> D[m][n]=qb1pre[m] ---
    {
        bfrag qf0, qf1;
        const float* qp = q + g * 8;
        float4 q0 = *reinterpret_cast<const float4*>(qp);
        float4 q1 = *reinterpret_cast<const float4*>(qp + 4);
        float4 q2 = *reinterpret_cast<const float4*>(qp + 32);
        float4 q3 = *reinterpret_cast<const float4*>(qp + 36);
        PACK(qf0, q0, q1); PACK(qf1, q2, q3);
        #pragma unroll
        for (int mt5 = 0; mt5 < 5; ++mt5) {
            bfrag aq0 = *reinterpret_cast<const bfrag*>(A1q + (((mt5 * 2 + 0) * 64 + lane) << 3));
            bfrag aq1 = *reinterpret_cast<const bfrag*>(A1q + (((mt5 * 2 + 1) * 64 + lane) << 3));
            f32x4 c = { 0.f, 0.f, 0.f, 0.f };
            c = __builtin_amdgcn_mfma_f32_16x16x32_bf16(aq0, qf0, c, 0, 0, 0);
            c = __builtin_amdgcn_mfma_f32_16x16x32_bf16(aq1, qf1, c, 0, 0, 0);
            float4 bv = *reinterpret_cast<const float4*>(b1 + mt5 * 16 + g * 4);
            if (l15 == 0) {
                float4 o = { c[0] + bv.x, c[1] + bv.y, c[2] + bv.z, c[3] + bv.w };
                *reinterpret_cast<float4*>(&qils[wv][mt5 * 16 + g * 4]) = o;
            }
        }
    }
    __syncthreads();   // the ONLY block barrier: LDS tables ready

    // --- fixed-base softmax state (per-lane partials, reduced in epilogue) ---
    float acc[16];
    #pragma unroll
    for (int j = 0; j < 16; ++j) acc[j] = 0.f;
    float Z = 0.f;

    // 1-deep prefetch of 32-row tiles
    float4 qa0, qa1, qa2, qa3, qb0, qb1_, qb2, qb3;
    LOADK32(0, qa0, qa1, qa2, qa3, qb0, qb1_, qb2, qb3);
    bfrag a0, a1, a2, a3;   // a0/a1 = group A feats; a2/a3 = group B
    PACK(a0, qa0, qa1); PACK(a1, qa2, qa3);
    PACK(a2, qb0, qb1_); PACK(a3, qb2, qb3);

    for (int mt = 0; mt < ntiles; ++mt) {
        if (mt + 1 < ntiles) { LOADK32(mt + 1, qa0, qa1, qa2, qa3, qb0, qb1_, qb2, qb3); }

        // GEMM1 group A -> sigmoid -> frags (d dead before group B: low liveness)
        bfrag xa0, xa1, xa2, xb0, xb1, xb2;
        {
            f32x4 d[5];
            #pragma unroll
            for (int mt5 = 0; mt5 < 5; ++mt5) {
                bfrag wA = *reinterpret_cast<const bfrag*>(&w1ls[((mt5 * 2 + 0) * 64 + lane) * 8]);
                bfrag wB = *reinterpret_cast<const bfrag*>(&w1ls[((mt5 * 2 + 1) * 64 + lane) * 8]);
                f32x4 c = *reinterpret_cast<const f32x4*>(&qils[wv][mt5 * 16 + g * 4]);
                c = __builtin_amdgcn_mfma_f32_16x16x32_bf16(wA, a0, c, 0, 0, 0);
                c = __builtin_amdgcn_mfma_f32_16x16x32_bf16(wB, a1, c, 0, 0, 0);
                d[mt5] = c;
            }
            #pragma unroll
            for (int j = 0; j < 8; ++j) {
                xa0[j] = (short)f2bf(sigmoid_fast(d[j >> 2][j & 3]));
                xa1[j] = (short)f2bf(sigmoid_fast(d[(8 + j) >> 2][(8 + j) & 3]));
                xa2[j] = (short)((16 + j) < 20
                            ? f2bf(sigmoid_fast(d[(16 + j) >> 2][(16 + j) & 3])) : 0);
            }
        }
        // GEMM1 group B -> sigmoid -> frags
        {
            f32x4 d[5];
            #pragma unroll
            for (int mt5 = 0; mt5 < 5; ++mt5) {
                bfrag wA = *reinterpret_cast<const bfrag*>(&w1ls[((mt5 * 2 + 0) * 64 + lane) * 8]);
                bfrag wB = *reinterpret_cast<const bfrag*>(&w1ls[((mt5 * 2 + 1) * 64 + lane) * 8]);
                f32x4 c = *reinterpret_cast<const f32x4*>(&qils[wv][mt5 * 16 + g * 4]);
                c = __builtin_amdgcn_mfma_f32_16x16x32_bf16(wA, a2, c, 0, 0, 0);
                c = __builtin_amdgcn_mfma_f32_16x16x32_bf16(wB, a3, c, 0, 0, 0);
                d[mt5] = c;
            }
            #pragma unroll
            for (int j = 0; j < 8; ++j) {
                xb0[j] = (short)f2bf(sigmoid_fast(d[j >> 2][j & 3]));
                xb1[j] = (short)f2bf(sigmoid_fast(d[(8 + j) >> 2][(8 + j) & 3]));
                xb2[j] = (short)((16 + j) < 20
                            ? f2bf(sigmoid_fast(d[(16 + j) >> 2][(16 + j) & 3])) : 0);
            }
        }

        // GEMM2 swapped + wk-dot folded; each u-frag read serves both groups
        float pa = 0.f, pb = 0.f;
        #pragma unroll
        for (int m2 = 0; m2 < 3; ++m2) {
            bfrag u0 = *reinterpret_cast<const bfrag*>(&w2ls[((m2 * 3 + 0) * 64 + lane) * 8]);
            bfrag u1 = *reinterpret_cast<const bfrag*>(&w2ls[((m2 * 3 + 1) * 64 + lane) * 8]);
            bfrag u2 = *reinterpret_cast<const bfrag*>(&w2ls[((m2 * 3 + 2) * 64 + lane) * 8]);
            f32x4 ci = *reinterpret_cast<const f32x4*>(&b2ls[m2 * 16 + g * 4]);
            f32x4 wv4 = *reinterpret_cast<const f32x4*>(&wkls[m2 * 16 + g * 4]);
            f32x4 ca = ci, cb = ci;
            ca = __builtin_amdgcn_mfma_f32_16x16x32_bf16(u0, xa0, ca, 0, 0, 0);
            ca = __builtin_amdgcn_mfma_f32_16x16x32_bf16(u1, xa1, ca, 0, 0, 0);
            ca = __builtin_amdgcn_mfma_f32_16x16x32_bf16(u2, xa2, ca, 0, 0, 0);
            cb = __builtin_amdgcn_mfma_f32_16x16x32_bf16(u0, xb0, cb, 0, 0, 0);
            cb = __builtin_amdgcn_mfma_f32_16x16x32_bf16(u1, xb1, cb, 0, 0, 0);
            cb = __builtin_amdgcn_mfma_f32_16x16x32_bf16(u2, xb2, cb, 0, 0, 0);
            #pragma unroll
            for (int rr = 0; rr < 4; ++rr) {
                pa = fmaf(sigmoid_fast(ca[rr]), wv4[rr], pa);
                pb = fmaf(sigmoid_fast(cb[rr]), wv4[rr], pb);
            }
        }
        pa += __shfl_xor(pa, 16); pa += __shfl_xor(pa, 32);
        pb += __shfl_xor(pb, 16); pb += __shfl_xor(pb, 32);

        // fixed-base exp weights; |score| <= sum|wk|+|bias| (~7.2) -> no overflow.
        const int ra = mt * 32 + l15, rb = ra + 16;
        float ea = (ra < len) ? __expf(pa + biass) : ((len == 0 && ra < TT) ? 1.f : 0.f);
        float eb = (rb < len) ? __expf(pb + biass) : ((len == 0 && rb < TT) ? 1.f : 0.f);
        Z += ea + eb;

        // fused pooling: both rows' keys still in the bf16 fragments
        #pragma unroll
        for (int j = 0; j < 8; ++j) {
            acc[j]     = fmaf(ea, bf2f((u16)a0[j]), fmaf(eb, bf2f((u16)a2[j]), acc[j]));
            acc[8 + j] = fmaf(ea, bf2f((u16)a1[j]), fmaf(eb, bf2f((u16)a3[j]), acc[8 + j]));
        }

        if (mt + 1 < ntiles) {
            PACK(a0, qa0, qa1); PACK(a1, qa2, qa3);
            PACK(a2, qb0, qb1_); PACK(a3, qb2, qb3);
        }
    }

    // reduce Z + pooled features over the 16 t-row lanes; lanes l15==0 write out
    Z += __shfl_xor(Z, 1); Z += __shfl_xor(Z, 2);
    Z += __shfl_xor(Z, 4); Z += __shfl_xor(Z, 8);
    #pragma unroll
    for (int j = 0; j < 16; ++j) {
        acc[j] += __shfl_xor(acc[j], 1);
        acc[j] += __shfl_xor(acc[j], 2);
        acc[j] += __shfl_xor(acc[j], 4);
        acc[j] += __shfl_xor(acc[j], 8);
    }
    if (l15 == 0) {
        float inv = __builtin_amdgcn_rcpf(Z);
        float* ob = out + (size_t)b * EE + g * 8;
        float4 o0 = { acc[0] * inv,  acc[1] * inv,  acc[2] * inv,  acc[3] * inv };
        float4 o1 = { acc[4] * inv,  acc[5] * inv,  acc[6] * inv,  acc[7] * inv };
        float4 o2 = { acc[8] * inv,  acc[9] * inv,  acc[10] * inv, acc[11] * inv };
        float4 o3 = { acc[12] * inv, acc[13] * inv, acc[14] * inv, acc[15] * inv };
        *reinterpret_cast<float4*>(ob)      = o0;
        *reinterpret_cast<float4*>(ob + 4)  = o1;
        *reinterpret_cast<float4*>(ob + 32) = o2;
        *reinterpret_cast<float4*>(ob + 36) = o3;
    }
}

extern "C" void kernel_launch(void* const* d_in, const int* in_sizes, int n_in,
                              void* d_out, int out_size, void* d_ws, size_t ws_size,
                              hipStream_t stream) {
    const float* queries = (const float*)d_in[0];
    const float* keys    = (const float*)d_in[1];
    const int*   klen    = (const int*)d_in[2];
    const float* W1      = (const float*)d_in[3];
    const float* b1      = (const float*)d_in[4];
    const float* W2      = (const float*)d_in[5];
    const float* b2      = (const float*)d_in[6];
    const float* wk      = (const float*)d_in[7];
    const float* bias    = (const float*)d_in[8];
    float* out           = (float*)d_out;

    u16* A1p = (u16*)d_ws;                                 // 10240 B
    u16* A2p = (u16*)((char*)d_ws + 10240);                //  9216 B
    u16* A1q = (u16*)((char*)d_ws + 19456);                // 10240 B

    prep_frags<<<20, 256, 0, stream>>>(W1, W2, A1p, A2p, A1q);
    din_mfma<<<1024, 256, 0, stream>>>(queries, keys, klen, b1, b2, wk, bias,
                                       A1p, A2p, A1q, out);
}